// Round 3
// baseline (658.850 us; speedup 1.0000x reference)
//
#include <hip/hip_runtime.h>

#define LDS_AS __attribute__((address_space(3)))
#define GLB_AS __attribute__((address_space(1)))

typedef __attribute__((ext_vector_type(8))) short bf16x8;    // 8 bf16 = 4 VGPRs (A/B frag)
typedef __attribute__((ext_vector_type(4))) float f32x4;     // 16x16 C/D frag
typedef __attribute__((ext_vector_type(16))) float f32x16;   // 32x32 C/D frag

static constexpr int NH = 4;
static constexpr int T  = 2048;
static constexpr int N  = 8192;
static constexpr int D  = 256;

__device__ inline unsigned short f2bf(float f) {
    unsigned int u = __float_as_uint(f);
    u += 0x7FFFu + ((u >> 16) & 1u);   // round-to-nearest-even
    return (unsigned short)(u >> 16);
}

__device__ inline void gl2lds16(const void* g, void* l) {
    __builtin_amdgcn_global_load_lds((GLB_AS void*)g, (LDS_AS void*)l, 16, 0, 0);
}

// ---------------- RoPE + bf16 cast: QR[h][t][n] ----------------
__global__ void rope_kernel(const float* __restrict__ Q, unsigned short* __restrict__ QR) {
    int g = blockIdx.x * 256 + threadIdx.x;     // one thread = 4 consecutive elements
    int base = g << 2;
    int n = base & (N - 1);
    int t = (base >> 13) & (T - 1);
    const float4 q = *(const float4*)(Q + (size_t)base);
    float tf = (float)t;
    const float inv2pi = 0.15915494309189535f;
    float f0 = exp2f((float)n       * (-1.0f / 512.0f)) * inv2pi;
    float f1 = exp2f((float)(n + 2) * (-1.0f / 512.0f)) * inv2pi;
    float r0 = tf * f0; r0 -= floorf(r0);
    float r1 = tf * f1; r1 -= floorf(r1);
    float s0 = __builtin_amdgcn_sinf(r0), c0 = __builtin_amdgcn_cosf(r0);
    float s1 = __builtin_amdgcn_sinf(r1), c1 = __builtin_amdgcn_cosf(r1);
    ushort4 o;
    o.x = f2bf(q.x * c0 - q.y * s0);
    o.y = f2bf(q.y * c0 + q.x * s0);
    o.z = f2bf(q.z * c1 - q.w * s1);
    o.w = f2bf(q.w * c1 + q.z * s1);
    *(ushort4*)(QR + (size_t)base) = o;
}

// ---------------- V -> Vt bf16 transpose via LDS: Vt[d][t] = bf16(V[t][d]) ----------------
__global__ void vt_kernel(const float* __restrict__ V, unsigned short* __restrict__ Vt) {
    __shared__ unsigned short tile[64 * 65];
    int tb = blockIdx.x >> 2, db = blockIdx.x & 3;
    int t0 = tb * 64, d0 = db * 64;
    int tid = threadIdx.x;
    #pragma unroll
    for (int r = 0; r < 16; r++) {
        int idx = tid + r * 256;
        int tl = idx >> 6, dl = idx & 63;
        tile[tl * 65 + dl] = f2bf(V[(size_t)(t0 + tl) * D + d0 + dl]);
    }
    __syncthreads();
    #pragma unroll
    for (int r = 0; r < 16; r++) {
        int idx = tid + r * 256;
        int dl = idx >> 6, tl = idx & 63;
        Vt[(size_t)(d0 + dl) * T + t0 + tl] = tile[tl * 65 + dl];
    }
}

// ---------------- GEMM1 v5: 128x256 tile, 32x32x16 MFMA, lane-ordered LDS, vmcnt(6) ----
// LDS layout (per buffer): A = 8 subtiles of 1024B, subtile blk=(rb*2+kk) holds rows
// [rb*32, rb*32+32) x k-half [kk*16, kk*16+16) in MFMA-lane order: lane l's 16B at
// l*16 = A[rb*32 + (l&31)][kk*16 + (l>>5)*8 ..+7]. B = 16 subtiles likewise.
// => every ds_read_b128 is base + lane*16B: fully linear, conflict-free.
// global_load_lds writes LDS linearly (base + lane*16B), so the permutation is applied
// on the GLOBAL source address per lane (m173 pattern); dst stays linear.
// Pipeline: triple buffer, depth-2 prefetch, s_waitcnt vmcnt(6) (tile t+1 in flight),
// raw s_barrier; never drain in the main loop.
__global__ __launch_bounds__(256, 2) void gemm1_kernel(const unsigned short* __restrict__ QR,
                                                       unsigned short* __restrict__ S, int KS) {
    __shared__ __align__(16) unsigned short As[3][4096];   // 8 KB each
    __shared__ __align__(16) unsigned short Bs[3][8192];   // 16 KB each (total 72 KB)

    int bx = blockIdx.x;
    int per_h = 72 * KS;
    int h = bx / per_h;
    int rem = bx % per_h;
    int task = rem / KS;
    int ksp = rem % KS;
    // decode (bi, bj): bj in [0, bi/2]; counts 1,1,2,2,...,8,8 sum=72
    int bi = 0, cum = 0;
    for (; bi < 16; bi++) { int nb = (bi >> 1) + 1; if (cum + nb > task) break; cum += nb; }
    int bj = task - cum;

    const unsigned short* A = QR + (size_t)h * T * N + (size_t)bi * 128 * N;
    const unsigned short* B = QR + (size_t)h * T * N + (size_t)bj * 256 * N;

    int KN = N / KS;
    int k_begin = ksp * KN;
    int nit = KN / 32;

    int tid = threadIdx.x;
    int lane = tid & 63, wave = tid >> 6;
    int wm = wave >> 1, wn = wave & 1;

    // staging source pre-swizzle: thread tid writes LDS bytes tid*16 of each 4KB chunk;
    // that slot must hold row rbA*32+(l&31), k-offset kkA (see layout comment above).
    int blk0 = wave;                               // subtile index of chunk 0
    int rowA = ((blk0 >> 1) << 5) + (lane & 31);   // in [0,64)
    int kkA  = ((blk0 & 1) << 4) + ((lane >> 5) << 3);
    const unsigned short* Asrc = A + (size_t)rowA * N + kkA;
    const unsigned short* Bsrc = B + (size_t)rowA * N + kkA;

    f32x16 acc[2][4];
    #pragma unroll
    for (int i = 0; i < 2; i++)
        #pragma unroll
        for (int j = 0; j < 4; j++)
            #pragma unroll
            for (int r = 0; r < 16; r++) acc[i][j][r] = 0.0f;

    // prologue: stage tiles 0 and 1 into buffers 0 and 1 (12 loads in flight)
    #pragma unroll
    for (int p = 0; p < 2; p++) {
        int k0 = k_begin + p * 32;
        gl2lds16(Asrc + k0,                   &As[p][tid * 8]);
        gl2lds16(Asrc + (size_t)64 * N + k0,  &As[p][2048 + tid * 8]);
        gl2lds16(Bsrc + k0,                   &Bs[p][tid * 8]);
        gl2lds16(Bsrc + (size_t)64 * N + k0,  &Bs[p][2048 + tid * 8]);
        gl2lds16(Bsrc + (size_t)128 * N + k0, &Bs[p][4096 + tid * 8]);
        gl2lds16(Bsrc + (size_t)192 * N + k0, &Bs[p][6144 + tid * 8]);
    }

    int cur = 0, nxt2 = 2;   // buffer of tile it, buffer of tile it+2
    for (int it = 0; it < nit; it++) {
        if (it + 1 < nit) {
            asm volatile("s_waitcnt vmcnt(6)" ::: "memory");   // tile it landed (own 6)
        } else {
            asm volatile("s_waitcnt vmcnt(0)" ::: "memory");   // final tile: drain
        }
        __builtin_amdgcn_s_barrier();            // block-wide: tile it valid, t-1 reads done
        __builtin_amdgcn_sched_barrier(0);       // pin ds_reads below the barrier

        bf16x8 a2[2][2], b2[4][2];
        #pragma unroll
        for (int i = 0; i < 2; i++)
            #pragma unroll
            for (int kk = 0; kk < 2; kk++)
                a2[i][kk] = *(const bf16x8*)&As[cur][(((wm * 2 + i) * 2 + kk) << 9) + lane * 8];
        #pragma unroll
        for (int j = 0; j < 4; j++)
            #pragma unroll
            for (int kk = 0; kk < 2; kk++)
                b2[j][kk] = *(const bf16x8*)&Bs[cur][(((wn * 4 + j) * 2 + kk) << 9) + lane * 8];

        if (it + 2 < nit) {                      // stage tile it+2 (overwrites buf of it-1)
            int k0 = k_begin + (it + 2) * 32;
            gl2lds16(Asrc + k0,                   &As[nxt2][tid * 8]);
            gl2lds16(Asrc + (size_t)64 * N + k0,  &As[nxt2][2048 + tid * 8]);
            gl2lds16(Bsrc + k0,                   &Bs[nxt2][tid * 8]);
            gl2lds16(Bsrc + (size_t)64 * N + k0,  &Bs[nxt2][2048 + tid * 8]);
            gl2lds16(Bsrc + (size_t)128 * N + k0, &Bs[nxt2][4096 + tid * 8]);
            gl2lds16(Bsrc + (size_t)192 * N + k0, &Bs[nxt2][6144 + tid * 8]);
        }

        __builtin_amdgcn_s_setprio(1);
        #pragma unroll
        for (int kk = 0; kk < 2; kk++)
            #pragma unroll
            for (int j = 0; j < 4; j++)
                #pragma unroll
                for (int i = 0; i < 2; i++)
                    acc[i][j] = __builtin_amdgcn_mfma_f32_32x32x16_bf16(a2[i][kk], b2[j][kk],
                                                                        acc[i][j], 0, 0, 0);
        __builtin_amdgcn_s_setprio(0);

        cur  = (cur  == 2) ? 0 : cur  + 1;
        nxt2 = (nxt2 == 2) ? 0 : nxt2 + 1;
    }

    // epilogue: 32x32 C/D layout col = lane&31, row = (reg&3) + 8*(reg>>2) + 4*(lane>>5)
    // [m74/m101]; strictly-lower causal mask s < t.
    unsigned short* Sh = S + (size_t)ksp * NH * T * T + (size_t)h * T * T;
    int col = lane & 31;
    int rbase = (lane >> 5) * 4;
    #pragma unroll
    for (int i = 0; i < 2; i++) {
        #pragma unroll
        for (int j = 0; j < 4; j++) {
            int s_g = bj * 256 + wn * 128 + j * 32 + col;
            #pragma unroll
            for (int reg = 0; reg < 16; reg++) {
                int t_g = bi * 128 + wm * 64 + i * 32 + (reg & 3) + 8 * (reg >> 2) + rbase;
                float v = (s_g < t_g) ? acc[i][j][reg] : 0.0f;
                Sh[(size_t)t_g * T + s_g] = f2bf(v);
            }
        }
    }
}

// ---------------- GEMM2 v2: double-buffered LDS, 1 barrier/iter, B reg-hoist ----------
// grid = NH * 2(dblk) * 72(chunk tasks, 256-wide); flattened loop is k0-major/ks-minor so
// the Vt tile is staged once per k0 (and its frags live in registers across KS ks-iters).
__global__ __launch_bounds__(256) void gemm2_kernel(const unsigned short* __restrict__ S,
                                                    const unsigned short* __restrict__ Vt,
                                                    float* __restrict__ out, int KS) {
    __shared__ __align__(16) unsigned short As[2][128 * 32];   // 8 KB each
    __shared__ __align__(16) unsigned short Bs[2][128 * 32];   // 8 KB each

    int bx = blockIdx.x;
    int per_h = 2 * 72;
    int h = bx / per_h;
    int rem = bx % per_h;
    int dblk = rem / 72;
    int tc = rem % 72;
    // decode (bi, chunk): nc(bi) = ceil((bi+1)*128/256) = (bi+2)>>1, sum = 72
    int bi = 0, cum = 0;
    for (; bi < 16; bi++) { int nc = (bi + 2) >> 1; if (cum + nc > tc) break; cum += nc; }
    int c = tc - cum;

    int kend = (bi + 1) * 128;
    int cstart = c * 256;
    int clen = min(256, kend - cstart);   // 128 or 256
    int cpk = clen >> 5;                  // K-steps per ks: 4 or 8
    int ls = (KS == 4) ? 2 : (KS == 2) ? 1 : 0;
    int nit = cpk << ls;                  // total flattened iterations

    const unsigned short* Sh = S + (size_t)h * T * T + (size_t)bi * 128 * T + cstart;
    const size_t sstride = (size_t)NH * T * T;      // stride between ks split buffers
    const unsigned short* B = Vt + (size_t)dblk * 128 * T + cstart;

    int tid = threadIdx.x;
    int lane = tid & 63, wave = tid >> 6;
    int wm = wave >> 1, wn = wave & 1;
    int quad = lane >> 4, l16 = lane & 15;
    int srow = tid >> 2;
    int scol = (tid & 3) * 8;

    f32x4 acc[4][4];
    #pragma unroll
    for (int i = 0; i < 4; i++)
        #pragma unroll
        for (int j = 0; j < 4; j++)
            #pragma unroll
            for (int r = 0; r < 4; r++) acc[i][j][r] = 0.0f;

    // prologue: stage iter 0 (ks=0, k0=0) into buffer 0
    gl2lds16(Sh + (size_t)srow * T + scol,        &As[0][srow * 32 + scol]);
    gl2lds16(Sh + (size_t)(srow + 64) * T + scol, &As[0][(srow + 64) * 32 + scol]);
    gl2lds16(B + (size_t)srow * T + scol,         &Bs[0][srow * 32 + scol]);
    gl2lds16(B + (size_t)(srow + 64) * T + scol,  &Bs[0][(srow + 64) * 32 + scol]);

    bf16x8 b[4];
    for (int i = 0; i < nit; i++) {
        int k0i = i >> ls;
        int ks  = i & (KS - 1);
        __syncthreads();   // drains vmcnt: current buffers were staged a full iter ago
        if (i + 1 < nit) {
            int ksn = (i + 1) & (KS - 1);
            int k0n = (i + 1) >> ls;
            const unsigned short* An = Sh + (size_t)ksn * sstride + k0n * 32;
            int pan = (i + 1) & 1;
            gl2lds16(An + (size_t)srow * T + scol,        &As[pan][srow * 32 + scol]);
            gl2lds16(An + (size_t)(srow + 64) * T + scol, &As[pan][(srow + 64) * 32 + scol]);
            if (ksn == 0) {   // next iter starts a new k0 -> fresh Vt tile
                const unsigned short* Bn = B + k0n * 32;
                int pbn = k0n & 1;
                gl2lds16(Bn + (size_t)srow * T + scol,        &Bs[pbn][srow * 32 + scol]);
                gl2lds16(Bn + (size_t)(srow + 64) * T + scol, &Bs[pbn][(srow + 64) * 32 + scol]);
            }
        }

        int pa = i & 1, pb = k0i & 1;
        if (ks == 0) {   // Vt frags are identical across the KS ks-iterations of this k0
            #pragma unroll
            for (int j = 0; j < 4; j++)
                b[j] = *(const bf16x8*)&Bs[pb][(wn * 64 + j * 16 + l16) * 32 + quad * 8];
        }
        bf16x8 a[4];
        #pragma unroll
        for (int ii = 0; ii < 4; ii++)
            a[ii] = *(const bf16x8*)&As[pa][(wm * 64 + ii * 16 + l16) * 32 + quad * 8];
        #pragma unroll
        for (int ii = 0; ii < 4; ii++)
            #pragma unroll
            for (int j = 0; j < 4; j++)
                acc[ii][j] = __builtin_amdgcn_mfma_f32_16x16x32_bf16(a[ii], b[j], acc[ii][j], 0, 0, 0);
    }

    float* oh = out + (size_t)h * T * D;
    #pragma unroll
    for (int i = 0; i < 4; i++) {
        int t_base = bi * 128 + wm * 64 + i * 16 + quad * 4;
        #pragma unroll
        for (int j = 0; j < 4; j++) {
            int d_g = dblk * 128 + wn * 64 + j * 16 + l16;
            #pragma unroll
            for (int r = 0; r < 4; r++) {
                int t_g = t_base + r;
                atomicAdd(&oh[(size_t)t_g * D + d_g], acc[i][j][r]);
            }
        }
    }
}

extern "C" void kernel_launch(void* const* d_in, const int* in_sizes, int n_in,
                              void* d_out, int out_size, void* d_ws, size_t ws_size,
                              hipStream_t stream) {
    const float* Q = (const float*)d_in[0];   // (1, 4, 2048, 8192) fp32
    const float* V = (const float*)d_in[1];   // (1, 1, 2048, 256)  fp32
    float* out = (float*)d_out;               // (1, 4, 2048, 256)  fp32

    const size_t qr_elems = (size_t)NH * T * N;   // 67.1M
    const size_t vt_elems = (size_t)D * T;        // 0.5M
    const size_t s_elems  = (size_t)NH * T * T;   // 16.8M per split

    // largest KS in {4,2,1} that fits (KS must divide N/32 -> powers of 2)
    int KS = 1;
    for (int cand : {4, 2, 1}) {
        if (ws_size >= (qr_elems + vt_elems + (size_t)cand * s_elems) * sizeof(unsigned short)) {
            KS = cand; break;
        }
    }
    if (ws_size < (qr_elems + vt_elems + (size_t)KS * s_elems) * sizeof(unsigned short)) return;

    unsigned short* QR = (unsigned short*)d_ws;
    unsigned short* Vt = QR + qr_elems;
    unsigned short* S  = Vt + vt_elems;   // KS consecutive buffers of s_elems

    rope_kernel<<<(NH * T * N / 4) / 256, 256, 0, stream>>>(Q, QR);
    vt_kernel<<<(T / 64) * (D / 64), 256, 0, stream>>>(V, Vt);
    gemm1_kernel<<<NH * 72 * KS, 256, 0, stream>>>(QR, S, KS);
    hipMemsetAsync(d_out, 0, (size_t)out_size * sizeof(float), stream);
    gemm2_kernel<<<NH * 2 * 72, 256, 0, stream>>>(S, Vt, out, KS);
}

// Round 4
// 588.900 us; speedup vs baseline: 1.1188x; 1.1188x over previous
//
#include <hip/hip_runtime.h>

#define LDS_AS __attribute__((address_space(3)))
#define GLB_AS __attribute__((address_space(1)))

typedef __attribute__((ext_vector_type(8))) short bf16x8;    // 8 bf16 = 4 VGPRs (A/B frag)
typedef __attribute__((ext_vector_type(4))) float f32x4;     // 16x16 C/D frag
typedef __attribute__((ext_vector_type(16))) float f32x16;   // 32x32 C/D frag

static constexpr int NH = 4;
static constexpr int T  = 2048;
static constexpr int N  = 8192;
static constexpr int D  = 256;

__device__ inline unsigned short f2bf(float f) {
    unsigned int u = __float_as_uint(f);
    u += 0x7FFFu + ((u >> 16) & 1u);   // round-to-nearest-even
    return (unsigned short)(u >> 16);
}

__device__ inline void gl2lds16(const void* g, void* l) {
    __builtin_amdgcn_global_load_lds((GLB_AS void*)g, (LDS_AS void*)l, 16, 0, 0);
}

// ---------------- RoPE + bf16 cast: QR[h][t][n] ----------------
__global__ void rope_kernel(const float* __restrict__ Q, unsigned short* __restrict__ QR) {
    int g = blockIdx.x * 256 + threadIdx.x;     // one thread = 4 consecutive elements
    int base = g << 2;
    int n = base & (N - 1);
    int t = (base >> 13) & (T - 1);
    const float4 q = *(const float4*)(Q + (size_t)base);
    float tf = (float)t;
    const float inv2pi = 0.15915494309189535f;
    float f0 = exp2f((float)n       * (-1.0f / 512.0f)) * inv2pi;
    float f1 = exp2f((float)(n + 2) * (-1.0f / 512.0f)) * inv2pi;
    float r0 = tf * f0; r0 -= floorf(r0);
    float r1 = tf * f1; r1 -= floorf(r1);
    float s0 = __builtin_amdgcn_sinf(r0), c0 = __builtin_amdgcn_cosf(r0);
    float s1 = __builtin_amdgcn_sinf(r1), c1 = __builtin_amdgcn_cosf(r1);
    ushort4 o;
    o.x = f2bf(q.x * c0 - q.y * s0);
    o.y = f2bf(q.y * c0 + q.x * s0);
    o.z = f2bf(q.z * c1 - q.w * s1);
    o.w = f2bf(q.w * c1 + q.z * s1);
    *(ushort4*)(QR + (size_t)base) = o;
}

// ---------------- V -> Vt bf16 transpose via LDS: Vt[d][t] = bf16(V[t][d]) ----------------
__global__ void vt_kernel(const float* __restrict__ V, unsigned short* __restrict__ Vt) {
    __shared__ unsigned short tile[64 * 65];
    int tb = blockIdx.x >> 2, db = blockIdx.x & 3;
    int t0 = tb * 64, d0 = db * 64;
    int tid = threadIdx.x;
    #pragma unroll
    for (int r = 0; r < 16; r++) {
        int idx = tid + r * 256;
        int tl = idx >> 6, dl = idx & 63;
        tile[tl * 65 + dl] = f2bf(V[(size_t)(t0 + tl) * D + d0 + dl]);
    }
    __syncthreads();
    #pragma unroll
    for (int r = 0; r < 16; r++) {
        int idx = tid + r * 256;
        int dl = idx >> 6, tl = idx & 63;
        Vt[(size_t)(d0 + dl) * T + t0 + tl] = tile[tl * 65 + dl];
    }
}

// ---------------- GEMM1 v6: 128x256 tile, 32x32x16 MFMA, swizzled row-major LDS ------
// LDS: row-major [rows][32 shorts] (64B rows), 16B slot q of row r holds global k-slot
// q ^ ((r>>1)&3). Swizzle is WITHIN-ROW -> staging stays v4-coalesced (16 x 64B
// segments per instruction); reads spread uniformly over all 8 bank-groups
// (parity(r) x slot hits each combo equally) -> zero conflicts.
// Pipeline: triple buffer, depth-2 prefetch, s_waitcnt vmcnt(6), raw s_barrier.
__global__ __launch_bounds__(256, 2) void gemm1_kernel(const unsigned short* __restrict__ QR,
                                                       unsigned short* __restrict__ S, int KS) {
    __shared__ __align__(16) unsigned short As[3][4096];   // 8 KB each  (128 rows x 32)
    __shared__ __align__(16) unsigned short Bs[3][8192];   // 16 KB each (256 rows x 32)

    int bx = blockIdx.x;
    int per_h = 72 * KS;
    int h = bx / per_h;
    int rem = bx % per_h;
    int task = rem / KS;
    int ksp = rem % KS;
    // decode (bi, bj): bj in [0, bi/2]; counts 1,1,2,2,...,8,8 sum=72
    int bi = 0, cum = 0;
    for (; bi < 16; bi++) { int nb = (bi >> 1) + 1; if (cum + nb > task) break; cum += nb; }
    int bj = task - cum;

    const unsigned short* A = QR + (size_t)h * T * N + (size_t)bi * 128 * N;
    const unsigned short* B = QR + (size_t)h * T * N + (size_t)bj * 256 * N;

    int KN = N / KS;
    int k_begin = ksp * KN;
    int nit = KN / 32;

    int tid = threadIdx.x;
    int lane = tid & 63, wave = tid >> 6;
    int wm = wave >> 1, wn = wave & 1;

    // staging: thread tid -> LDS bytes tid*16 (linear, = row srow slot q); global src
    // reads slot q ^ ((srow>>1)&3) of the same row -> within-row permute, coalesced.
    int srow = tid >> 2;
    int q = tid & 3;
    int scol_sw = (q ^ ((srow >> 1) & 3)) * 8;
    const unsigned short* Asrc = A + (size_t)srow * N + scol_sw;
    const unsigned short* Bsrc = B + (size_t)srow * N + scol_sw;
    // (+64/128/192 rows keep (row>>1)&3 unchanged, so same scol_sw applies)

    f32x16 acc[2][4];
    #pragma unroll
    for (int i = 0; i < 2; i++)
        #pragma unroll
        for (int j = 0; j < 4; j++)
            #pragma unroll
            for (int r = 0; r < 16; r++) acc[i][j][r] = 0.0f;

    // prologue: stage tiles 0 and 1 into buffers 0 and 1 (12 loads in flight)
    #pragma unroll
    for (int p = 0; p < 2; p++) {
        int k0 = k_begin + p * 32;
        gl2lds16(Asrc + k0,                   &As[p][tid * 8]);
        gl2lds16(Asrc + (size_t)64 * N + k0,  &As[p][2048 + tid * 8]);
        gl2lds16(Bsrc + k0,                   &Bs[p][tid * 8]);
        gl2lds16(Bsrc + (size_t)64 * N + k0,  &Bs[p][2048 + tid * 8]);
        gl2lds16(Bsrc + (size_t)128 * N + k0, &Bs[p][4096 + tid * 8]);
        gl2lds16(Bsrc + (size_t)192 * N + k0, &Bs[p][6144 + tid * 8]);
    }

    // MFMA 32x32x16 fragment read: lane l needs row rb*32+(l&31), k-half kk,
    // 8 shorts at (l>>5)*8 -> global slot kk*2+(l>>5), LDS slot ^= (l>>1)&3.
    int l31 = lane & 31, hi = lane >> 5, fl = (lane >> 1) & 3;

    int cur = 0, nxt2 = 2;   // buffer of tile it, buffer of tile it+2
    for (int it = 0; it < nit; it++) {
        if (it + 1 < nit) {
            asm volatile("s_waitcnt vmcnt(6)" ::: "memory");   // tile it landed (own 6)
        } else {
            asm volatile("s_waitcnt vmcnt(0)" ::: "memory");   // final tile: drain
        }
        __builtin_amdgcn_s_barrier();            // block-wide: tile it valid, t-1 reads done
        __builtin_amdgcn_sched_barrier(0);       // pin ds_reads below the barrier

        bf16x8 a2[2][2], b2[4][2];
        #pragma unroll
        for (int i = 0; i < 2; i++)
            #pragma unroll
            for (int kk = 0; kk < 2; kk++)
                a2[i][kk] = *(const bf16x8*)&As[cur][(wm * 64 + i * 32 + l31) * 32
                                                     + ((kk * 2 + hi) ^ fl) * 8];
        #pragma unroll
        for (int j = 0; j < 4; j++)
            #pragma unroll
            for (int kk = 0; kk < 2; kk++)
                b2[j][kk] = *(const bf16x8*)&Bs[cur][(wn * 128 + j * 32 + l31) * 32
                                                     + ((kk * 2 + hi) ^ fl) * 8];

        if (it + 2 < nit) {                      // stage tile it+2 (overwrites buf of it-1)
            int k0 = k_begin + (it + 2) * 32;
            gl2lds16(Asrc + k0,                   &As[nxt2][tid * 8]);
            gl2lds16(Asrc + (size_t)64 * N + k0,  &As[nxt2][2048 + tid * 8]);
            gl2lds16(Bsrc + k0,                   &Bs[nxt2][tid * 8]);
            gl2lds16(Bsrc + (size_t)64 * N + k0,  &Bs[nxt2][2048 + tid * 8]);
            gl2lds16(Bsrc + (size_t)128 * N + k0, &Bs[nxt2][4096 + tid * 8]);
            gl2lds16(Bsrc + (size_t)192 * N + k0, &Bs[nxt2][6144 + tid * 8]);
        }

        __builtin_amdgcn_s_setprio(1);
        #pragma unroll
        for (int kk = 0; kk < 2; kk++)
            #pragma unroll
            for (int j = 0; j < 4; j++)
                #pragma unroll
                for (int i = 0; i < 2; i++)
                    acc[i][j] = __builtin_amdgcn_mfma_f32_32x32x16_bf16(a2[i][kk], b2[j][kk],
                                                                        acc[i][j], 0, 0, 0);
        __builtin_amdgcn_s_setprio(0);

        cur  = (cur  == 2) ? 0 : cur  + 1;
        nxt2 = (nxt2 == 2) ? 0 : nxt2 + 1;
    }

    // epilogue: 32x32 C/D layout col = lane&31, row = (reg&3) + 8*(reg>>2) + 4*(lane>>5)
    // [m74/m101, verified correct in round 3]; strictly-lower causal mask s < t.
    unsigned short* Sh = S + (size_t)ksp * NH * T * T + (size_t)h * T * T;
    int col = lane & 31;
    int rbase = (lane >> 5) * 4;
    #pragma unroll
    for (int i = 0; i < 2; i++) {
        #pragma unroll
        for (int j = 0; j < 4; j++) {
            int s_g = bj * 256 + wn * 128 + j * 32 + col;
            #pragma unroll
            for (int reg = 0; reg < 16; reg++) {
                int t_g = bi * 128 + wm * 64 + i * 32 + (reg & 3) + 8 * (reg >> 2) + rbase;
                float v = (s_g < t_g) ? acc[i][j][reg] : 0.0f;
                Sh[(size_t)t_g * T + s_g] = f2bf(v);
            }
        }
    }
}

// ---------------- GEMM2 v3: counted-vmcnt triple-buffer pipeline + swizzled LDS ------
// grid = NH * 2(dblk) * 72(chunk tasks, 256-wide). Flattened (k0-major, ks-minor) loop;
// uniform 4 gl2lds per tile (A 2 + B 2; B restage per ks is L2-hot, cost ~3us total).
// Same hazard structure as gemm1 v6 with vmcnt(4).
__global__ __launch_bounds__(256, 2) void gemm2_kernel(const unsigned short* __restrict__ S,
                                                       const unsigned short* __restrict__ Vt,
                                                       float* __restrict__ out, int KS) {
    __shared__ __align__(16) unsigned short As[3][4096];   // 8 KB each (128 rows x 32)
    __shared__ __align__(16) unsigned short Bs[3][4096];   // 8 KB each

    int bx = blockIdx.x;
    int per_h = 2 * 72;
    int h = bx / per_h;
    int rem = bx % per_h;
    int dblk = rem / 72;
    int tc = rem % 72;
    // decode (bi, chunk): nc(bi) = ceil((bi+1)*128/256) = (bi+2)>>1, sum = 72
    int bi = 0, cum = 0;
    for (; bi < 16; bi++) { int nc = (bi + 2) >> 1; if (cum + nc > tc) break; cum += nc; }
    int c = tc - cum;

    int kend = (bi + 1) * 128;
    int cstart = c * 256;
    int clen = min(256, kend - cstart);   // 128 or 256
    int cpk = clen >> 5;                  // K-steps per ks: 4 or 8
    int ls = (KS == 4) ? 2 : (KS == 2) ? 1 : 0;
    int nit = cpk << ls;                  // total flattened iterations (>= 4)

    const unsigned short* Sh = S + (size_t)h * T * T + (size_t)bi * 128 * T + cstart;
    const size_t sstride = (size_t)NH * T * T;      // stride between ks split buffers
    const unsigned short* B = Vt + (size_t)dblk * 128 * T + cstart;

    int tid = threadIdx.x;
    int lane = tid & 63, wave = tid >> 6;
    int wm = wave >> 1, wn = wave & 1;
    int quad = lane >> 4, l16 = lane & 15;

    // staging swizzle (same as gemm1): src slot = q ^ ((srow>>1)&3), dst linear tid*16B
    int srow = tid >> 2;
    int q = tid & 3;
    int scol_sw = (q ^ ((srow >> 1) & 3)) * 8;

    f32x4 acc[4][4];
    #pragma unroll
    for (int i = 0; i < 4; i++)
        #pragma unroll
        for (int j = 0; j < 4; j++)
            #pragma unroll
            for (int r = 0; r < 4; r++) acc[i][j][r] = 0.0f;

    // prologue: stage tiles 0 and 1 into buffers 0 and 1 (8 loads in flight)
    #pragma unroll
    for (int p = 0; p < 2; p++) {
        int ks0 = p & (KS - 1);
        int k00 = (p >> ls) * 32;
        const unsigned short* An = Sh + (size_t)ks0 * sstride + k00;
        const unsigned short* Bn = B + k00;
        gl2lds16(An + (size_t)srow * T + scol_sw,        &As[p][tid * 8]);
        gl2lds16(An + (size_t)(srow + 64) * T + scol_sw, &As[p][2048 + tid * 8]);
        gl2lds16(Bn + (size_t)srow * T + scol_sw,        &Bs[p][tid * 8]);
        gl2lds16(Bn + (size_t)(srow + 64) * T + scol_sw, &Bs[p][2048 + tid * 8]);
    }

    int fl16 = (l16 >> 1) & 3;   // read-side swizzle for 16x16 frags
    int cur = 0, nxt2 = 2;
    for (int i = 0; i < nit; i++) {
        if (i + 1 < nit) {
            asm volatile("s_waitcnt vmcnt(4)" ::: "memory");   // tile i landed (own 4)
        } else {
            asm volatile("s_waitcnt vmcnt(0)" ::: "memory");
        }
        __builtin_amdgcn_s_barrier();
        __builtin_amdgcn_sched_barrier(0);

        bf16x8 a[4], b[4];
        #pragma unroll
        for (int ii = 0; ii < 4; ii++) {
            a[ii] = *(const bf16x8*)&As[cur][(wm * 64 + ii * 16 + l16) * 32 + (quad ^ fl16) * 8];
            b[ii] = *(const bf16x8*)&Bs[cur][(wn * 64 + ii * 16 + l16) * 32 + (quad ^ fl16) * 8];
        }

        if (i + 2 < nit) {
            int ksn = (i + 2) & (KS - 1);
            int k0n = ((i + 2) >> ls) * 32;
            const unsigned short* An = Sh + (size_t)ksn * sstride + k0n;
            const unsigned short* Bn = B + k0n;
            gl2lds16(An + (size_t)srow * T + scol_sw,        &As[nxt2][tid * 8]);
            gl2lds16(An + (size_t)(srow + 64) * T + scol_sw, &As[nxt2][2048 + tid * 8]);
            gl2lds16(Bn + (size_t)srow * T + scol_sw,        &Bs[nxt2][tid * 8]);
            gl2lds16(Bn + (size_t)(srow + 64) * T + scol_sw, &Bs[nxt2][2048 + tid * 8]);
        }

        __builtin_amdgcn_s_setprio(1);
        #pragma unroll
        for (int ii = 0; ii < 4; ii++)
            #pragma unroll
            for (int j = 0; j < 4; j++)
                acc[ii][j] = __builtin_amdgcn_mfma_f32_16x16x32_bf16(a[ii], b[j], acc[ii][j], 0, 0, 0);
        __builtin_amdgcn_s_setprio(0);

        cur  = (cur  == 2) ? 0 : cur  + 1;
        nxt2 = (nxt2 == 2) ? 0 : nxt2 + 1;
    }

    float* oh = out + (size_t)h * T * D;
    #pragma unroll
    for (int i = 0; i < 4; i++) {
        int t_base = bi * 128 + wm * 64 + i * 16 + quad * 4;
        #pragma unroll
        for (int j = 0; j < 4; j++) {
            int d_g = dblk * 128 + wn * 64 + j * 16 + l16;
            #pragma unroll
            for (int r = 0; r < 4; r++) {
                int t_g = t_base + r;
                atomicAdd(&oh[(size_t)t_g * D + d_g], acc[i][j][r]);
            }
        }
    }
}

extern "C" void kernel_launch(void* const* d_in, const int* in_sizes, int n_in,
                              void* d_out, int out_size, void* d_ws, size_t ws_size,
                              hipStream_t stream) {
    const float* Q = (const float*)d_in[0];   // (1, 4, 2048, 8192) fp32
    const float* V = (const float*)d_in[1];   // (1, 1, 2048, 256)  fp32
    float* out = (float*)d_out;               // (1, 4, 2048, 256)  fp32

    const size_t qr_elems = (size_t)NH * T * N;   // 67.1M
    const size_t vt_elems = (size_t)D * T;        // 0.5M
    const size_t s_elems  = (size_t)NH * T * T;   // 16.8M per split

    // largest KS in {4,2,1} that fits (KS must divide N/32 -> powers of 2)
    int KS = 1;
    for (int cand : {4, 2, 1}) {
        if (ws_size >= (qr_elems + vt_elems + (size_t)cand * s_elems) * sizeof(unsigned short)) {
            KS = cand; break;
        }
    }
    if (ws_size < (qr_elems + vt_elems + (size_t)KS * s_elems) * sizeof(unsigned short)) return;

    unsigned short* QR = (unsigned short*)d_ws;
    unsigned short* Vt = QR + qr_elems;
    unsigned short* S  = Vt + vt_elems;   // KS consecutive buffers of s_elems

    rope_kernel<<<(NH * T * N / 4) / 256, 256, 0, stream>>>(Q, QR);
    vt_kernel<<<(T / 64) * (D / 64), 256, 0, stream>>>(V, Vt);
    gemm1_kernel<<<NH * 72 * KS, 256, 0, stream>>>(QR, S, KS);
    hipMemsetAsync(d_out, 0, (size_t)out_size * sizeof(float), stream);
    gemm2_kernel<<<NH * 2 * 72, 256, 0, stream>>>(S, Vt, out, KS);
}